// Round 5
// baseline (362.882 us; speedup 1.0000x reference)
//
#include <hip/hip_runtime.h>

// Fused self-attention, B=32, H=W=64, C=256.
// PERSISTENT pipelined block: 8 waves = 8 channels, grid = 256 (1 block/CU),
// each block loops over 4 consecutive b. One WAVE per (b,c) chain.
//
// vs r3/r4: the mem<->compute serialization is removed INSIDE the block:
//  * LDS fixed roles: R0 = X stage (64KB), R1 = out stage (64KB).
//  * X fragments hoisted to regs (xf) right after the iter barrier -> R0 free
//    -> X(b+1) staged into R0 DURING M1-M3 of b (T14: issue-early/commit-late).
//  * Wq held in regs across iters; Wk prefetched per-iter before M1.
//    M1/M2/M4 are pure-register MFMA clusters.
//  * Raw barriers (s_waitcnt lgkmcnt(0) + s_barrier): in-flight global loads /
//    stores are NEVER drained at barriers (unlike __syncthreads' vmcnt(0)).
//  * Phase C overlaps next iter's xf-read; stores are issue-and-continue.
//  * Per-chain numerics identical to r3/r4 (same formulas, same order).

typedef short short8 __attribute__((ext_vector_type(8)));
typedef float floatx4 __attribute__((ext_vector_type(4)));
typedef unsigned int uint;

#define BAR() do { asm volatile("s_waitcnt lgkmcnt(0)" ::: "memory"); \
    __builtin_amdgcn_s_barrier(); __builtin_amdgcn_sched_barrier(0); } while (0)

__device__ __forceinline__ uint cvtpk(float a, float b) {  // pack 2 bf16 (RNE)
  uint r;
  asm("v_cvt_pk_bf16_f32 %0, %1, %2" : "=v"(r) : "v"(a), "v"(b));
  return r;
}
__device__ __forceinline__ short8 u4s8(uint a, uint b, uint c, uint d) {
  union { uint u[4]; short8 s; } t;
  t.u[0] = a; t.u[1] = b; t.u[2] = c; t.u[3] = d;
  return t.s;
}
__device__ __forceinline__ float hsg(float x) {
  return fminf(fmaxf(0.2f * x + 0.5f, 0.f), 1.f);
}

__device__ __forceinline__ void pl32swap(uint A, uint C, uint& lo, uint& hi, int quad) {
#if __has_builtin(__builtin_amdgcn_permlane32_swap)
  auto r = __builtin_amdgcn_permlane32_swap(A, C, false, false);
  lo = (uint)r[0]; hi = (uint)r[1];
#else
  uint sA = __shfl_xor(A, 32), sC = __shfl_xor(C, 32);
  bool up = quad >= 2;
  lo = up ? sC : A;
  hi = up ? C : sA;
#endif
}
__device__ __forceinline__ void pl16swap(uint A, uint C, uint& lo, uint& hi, int quad) {
#if __has_builtin(__builtin_amdgcn_permlane16_swap)
  auto r = __builtin_amdgcn_permlane16_swap(A, C, false, false);
  lo = (uint)r[0]; hi = (uint)r[1];
#else
  uint sA = (uint)__builtin_amdgcn_ds_swizzle((int)A, 0x401F);
  uint sC = (uint)__builtin_amdgcn_ds_swizzle((int)C, 0x401F);
  bool odd = quad & 1;
  lo = odd ? sC : A;
  hi = odd ? C : sA;
#endif
}
// C-layout words (k-pair idx 8kt+2quad+r) -> A/B-frag short8 (k-pair idx 16ks+4quad+u)
__device__ __forceinline__ short8 xchg4(uint A, uint B, uint C, uint D, int quad) {
  uint Ap, Cp, Bp, Dp, t0, t1, t2, t3;
  pl32swap(A, C, Ap, Cp, quad);
  pl32swap(B, D, Bp, Dp, quad);
  pl16swap(Ap, Cp, t0, t2, quad);
  pl16swap(Bp, Dp, t1, t3, quad);
  return u4s8(t0, t1, t2, t3);
}

// staging helpers: thread covers channels ch4*4..+3 of position-pairs grp
__device__ __forceinline__ void stage_issue(const float* xb, int grp, int i0,
                                            float4* va, float4* vb) {
#pragma unroll
  for (int i = 0; i < 4; ++i) {
    int pair = (i0 + i) * 256 + grp;
    int h = pair >> 5, w0 = (pair & 31) << 1;
    const float* src = xb + (size_t)(h * 64 + w0) * 256;
    va[i] = *(const float4*)src;
    vb[i] = *(const float4*)(src + 256);
  }
}
__device__ __forceinline__ void stage_commit(unsigned char* base0, int grp, int i0,
                                             const float4* va, const float4* vb) {
#pragma unroll
  for (int i = 0; i < 4; ++i) {
    int pair = (i0 + i) * 256 + grp;
    int h = pair >> 5, w0 = (pair & 31) << 1;
    uint off = (uint)(h * 128 + (((w0 >> 3) ^ (h & 7)) << 4) + ((w0 & 7) << 1));
    *(uint*)(base0 + 0 * 8192 + off) = cvtpk(va[i].x, vb[i].x);
    *(uint*)(base0 + 1 * 8192 + off) = cvtpk(va[i].y, vb[i].y);
    *(uint*)(base0 + 2 * 8192 + off) = cvtpk(va[i].z, vb[i].z);
    *(uint*)(base0 + 3 * 8192 + off) = cvtpk(va[i].w, vb[i].w);
  }
}
__device__ __forceinline__ void ld_xf(const unsigned char* buf0, int l15, int quad,
                                      short8 xf[4][2]) {
#pragma unroll
  for (int rt = 0; rt < 4; ++rt) {
    int r = rt * 16 + l15;
#pragma unroll
    for (int ks = 0; ks < 2; ++ks)
      xf[rt][ks] = *(const short8*)(buf0 + r * 128 + (((ks * 4 + quad) ^ (r & 7)) << 4));
  }
}

// ---- prep: Wq/Wk (C,64,64 f32) -> bf16 A-fragment layout in ws -------------
__global__ __launch_bounds__(256) void prep_w(const float* __restrict__ Wq,
                                              const float* __restrict__ Wk,
                                              unsigned short* __restrict__ ws) {
  __shared__ __align__(16) unsigned char sm[4 * 8704];
  const int tid = threadIdx.x, lane = tid & 63, wid = tid >> 6;
  const int task = blockIdx.x * 4 + wid;              // [0, 512)
  const int c = task & 255;
  const float* wp = ((task >> 8) ? Wk : Wq) + (size_t)c * 4096;
  unsigned char* buf = sm + wid * 8704;
  const int l15 = lane & 15, quad = lane >> 4;
#pragma unroll 4
  for (int j = 0; j < 16; ++j) {                      // stage [w][k], stride 136 B
    int f4 = j * 64 + lane;
    float4 v = *(const float4*)(wp + (size_t)f4 * 4);
    int w = f4 >> 4, k0 = (f4 & 15) << 2;
    uint2 pk; pk.x = cvtpk(v.x, v.y); pk.y = cvtpk(v.z, v.w);
    *(uint2*)(buf + w * 136 + k0 * 2) = pk;
  }
  unsigned short* dst = ws + (size_t)task * 4096;
#pragma unroll
  for (int kt = 0; kt < 4; ++kt)
#pragma unroll
    for (int ks = 0; ks < 2; ++ks) {                  // transposed u16 gather
      const unsigned short* p = (const unsigned short*)buf + (ks * 32 + quad * 8) * 68 + (kt * 16 + l15);
      short8 af = u4s8((uint)p[0]   | ((uint)p[68]  << 16),
                       (uint)p[136] | ((uint)p[204] << 16),
                       (uint)p[272] | ((uint)p[340] << 16),
                       (uint)p[408] | ((uint)p[476] << 16));
      *(short8*)(dst + ((kt * 2 + ks) * 64 + lane) * 8) = af;
    }
}

// ---- main ------------------------------------------------------------------
__global__ __launch_bounds__(512, 2) void fused_attn(
    const float* __restrict__ x, const unsigned short* __restrict__ wsp,
    float* __restrict__ out) {
  __shared__ __align__(16) unsigned char smem[2 * 8 * 8192];  // R0=X, R1=out

  const int tid  = threadIdx.x;
  const int lane = tid & 63;
  const int wid  = tid >> 6;                 // 0..7 = channel within block
  const int l15  = lane & 15;
  const int quad = lane >> 4;
  const int ch4  = tid & 1;                  // staging/output channel-half
  const int grp  = tid >> 1;

  const int cg8 = blockIdx.x & 31;           // consecutive blocks share x(b) lines
  const int bq  = blockIdx.x >> 5;           // b = bq*4 + it
  const int c0  = cg8 << 3;
  const int c   = c0 + wid;

  unsigned char* xbuf = smem + wid * 8192;            // own X tile (read)
  unsigned char* obuf = smem + 65536 + wid * 8192;    // own out tile (write)
  unsigned char* stb  = smem + ch4 * 32768;           // staging target base

  const short8* wqf = (const short8*)wsp + (size_t)c * 512;
  const short8* wkf = wqf + 256 * 512;

  // Wq fragments: loaded once, held across all 4 iterations
  short8 aq[4][2];
#pragma unroll
  for (int kt = 0; kt < 4; ++kt)
#pragma unroll
    for (int ks = 0; ks < 2; ++ks) aq[kt][ks] = wqf[(kt * 2 + ks) * 64 + lane];

  // ---- prologue: stage X(b0) into R0 ---------------------------------------
  {
    const float* xb = x + (size_t)(bq * 4) * 4096 * 256 + c0 + ch4 * 4;
    float4 va[4], vb[4];
    stage_issue(xb, grp, 0, va, vb);
    stage_commit(stb, grp, 0, va, vb);
    stage_issue(xb, grp, 4, va, vb);
    stage_commit(stb, grp, 4, va, vb);
  }
  BAR();
  short8 xf[4][2];
  ld_xf(xbuf, l15, quad, xf);
  BAR();                                     // all xf reads done -> R0 reusable

  const floatx4 zero4 = {0.f, 0.f, 0.f, 0.f};

  for (int it = 0; it < 4; ++it) {
    const bool pre = (it < 3);
    const float* xbn = x + (size_t)(bq * 4 + it + 1) * 4096 * 256 + c0 + ch4 * 4;
    float4 va[4], vb[4];
    if (pre) stage_issue(xbn, grp, 0, va, vb);        // X(b+1) bat0 in flight

    // Wk fragments for this iter: issue now, drain under M1
    short8 wkr[4][2];
#pragma unroll
    for (int kt = 0; kt < 4; ++kt)
#pragma unroll
      for (int ks = 0; ks < 2; ++ks) wkr[kt][ks] = wkf[(kt * 2 + ks) * 64 + lane];

    floatx4 acc[16];

    // ==== M1: qT = WqT x X (pure-register MFMA) =============================
#pragma unroll
    for (int i = 0; i < 16; ++i) acc[i] = zero4;
    __builtin_amdgcn_s_setprio(1);
#pragma unroll
    for (int kt = 0; kt < 4; ++kt)
#pragma unroll
      for (int ht = 0; ht < 4; ++ht) {
        acc[kt * 4 + ht] = __builtin_amdgcn_mfma_f32_16x16x32_bf16(aq[kt][0], xf[ht][0], acc[kt * 4 + ht], 0, 0, 0);
        acc[kt * 4 + ht] = __builtin_amdgcn_mfma_f32_16x16x32_bf16(aq[kt][1], xf[ht][1], acc[kt * 4 + ht], 0, 0, 0);
      }
    __builtin_amdgcn_s_setprio(0);

    // hard_sigmoid + in-register exchange -> qf[ht][ks]
    short8 qf[4][2];
#pragma unroll
    for (int ht = 0; ht < 4; ++ht) {
      uint s[4][2];
#pragma unroll
      for (int kt = 0; kt < 4; ++kt) {
        floatx4 a = acc[kt * 4 + ht];
        s[kt][0] = cvtpk(hsg(a[0]), hsg(a[1]));
        s[kt][1] = cvtpk(hsg(a[2]), hsg(a[3]));
      }
#pragma unroll
      for (int ks = 0; ks < 2; ++ks)
        qf[ht][ks] = xchg4(s[2 * ks][0], s[2 * ks][1], s[2 * ks + 1][0], s[2 * ks + 1][1], quad);
    }

    if (pre) {
      stage_commit(stb, grp, 0, va, vb);              // bat0 -> R0
      stage_issue(xbn, grp, 4, va, vb);               // bat1 in flight
    }

    // ==== M2: KT = WkT x X (pure-register MFMA) =============================
#pragma unroll
    for (int i = 0; i < 16; ++i) acc[i] = zero4;
    __builtin_amdgcn_s_setprio(1);
#pragma unroll
    for (int kt = 0; kt < 4; ++kt)
#pragma unroll
      for (int ht = 0; ht < 4; ++ht) {
        acc[kt * 4 + ht] = __builtin_amdgcn_mfma_f32_16x16x32_bf16(wkr[kt][0], xf[ht][0], acc[kt * 4 + ht], 0, 0, 0);
        acc[kt * 4 + ht] = __builtin_amdgcn_mfma_f32_16x16x32_bf16(wkr[kt][1], xf[ht][1], acc[kt * 4 + ht], 0, 0, 0);
      }
    __builtin_amdgcn_s_setprio(0);

    // tanh + in-register exchange -> kf[ht][ks]
    short8 kf[4][2];
#pragma unroll
    for (int ht = 0; ht < 4; ++ht) {
      uint t[4][2];
#pragma unroll
      for (int kt = 0; kt < 4; ++kt) {
        floatx4 a = acc[kt * 4 + ht];
        float kv[4];
#pragma unroll
        for (int i = 0; i < 4; ++i) {
          float e = __expf(2.f * a[i]);
          kv[i] = 1.f - 2.f / (e + 1.f);              // tanh
        }
        t[kt][0] = cvtpk(kv[0], kv[1]);
        t[kt][1] = cvtpk(kv[2], kv[3]);
      }
#pragma unroll
      for (int ks = 0; ks < 2; ++ks)
        kf[ht][ks] = xchg4(t[2 * ks][0], t[2 * ks][1], t[2 * ks + 1][0], t[2 * ks + 1][1], quad);
    }

    if (pre) stage_commit(stb, grp, 4, va, vb);       // bat1 -> R0 (va/vb die)

    // ==== M3: S = q x K^T, softmax; two wt-half passes ======================
    short8 sf[4][2];
#pragma unroll
    for (int ks2 = 0; ks2 < 2; ++ks2) {
      floatx4 a2[8];
#pragma unroll
      for (int i = 0; i < 8; ++i) a2[i] = zero4;
      __builtin_amdgcn_s_setprio(1);
#pragma unroll
      for (int mt = 0; mt < 4; ++mt)
#pragma unroll
        for (int wtl = 0; wtl < 2; ++wtl) {
          int wt = ks2 * 2 + wtl;
          a2[wtl * 4 + mt] = __builtin_amdgcn_mfma_f32_16x16x32_bf16(qf[wt][0], kf[mt][0], a2[wtl * 4 + mt], 0, 0, 0);
          a2[wtl * 4 + mt] = __builtin_amdgcn_mfma_f32_16x16x32_bf16(qf[wt][1], kf[mt][1], a2[wtl * 4 + mt], 0, 0, 0);
        }
      __builtin_amdgcn_s_setprio(0);
      // e = exp(hs(s)); hs in [0,1] -> no max subtraction needed
#pragma unroll
      for (int i = 0; i < 8; ++i)
#pragma unroll
        for (int j = 0; j < 4; ++j) a2[i][j] = __expf(hsg(a2[i][j]));
      float inv2[2][4];
#pragma unroll
      for (int wtl = 0; wtl < 2; ++wtl)
#pragma unroll
        for (int i = 0; i < 4; ++i) {                 // row sum: 3 adds + 4 shfls
          float pp = a2[wtl * 4 + 0][i] + a2[wtl * 4 + 1][i] + a2[wtl * 4 + 2][i] + a2[wtl * 4 + 3][i];
          pp += __shfl_xor(pp, 1, 16);
          pp += __shfl_xor(pp, 2, 16);
          pp += __shfl_xor(pp, 4, 16);
          pp += __shfl_xor(pp, 8, 16);
          inv2[wtl][i] = 1.f / pp;
        }
#pragma unroll
      for (int mt = 0; mt < 4; ++mt) {
        uint s0 = cvtpk(a2[mt][0] * inv2[0][0], a2[mt][1] * inv2[0][1]);
        uint s1 = cvtpk(a2[mt][2] * inv2[0][2], a2[mt][3] * inv2[0][3]);
        uint s2 = cvtpk(a2[4 + mt][0] * inv2[1][0], a2[4 + mt][1] * inv2[1][1]);
        uint s3 = cvtpk(a2[4 + mt][2] * inv2[1][2], a2[4 + mt][3] * inv2[1][3]);
        sf[mt][ks2] = xchg4(s0, s1, s2, s3, quad);
      }
    }

    // ==== M4: outT = SnT x X (pure-register MFMA) -> out into R1 ============
#pragma unroll
    for (int i = 0; i < 16; ++i) acc[i] = zero4;
    __builtin_amdgcn_s_setprio(1);
#pragma unroll
    for (int mt = 0; mt < 4; ++mt)
#pragma unroll
      for (int ht = 0; ht < 4; ++ht) {
        acc[mt * 4 + ht] = __builtin_amdgcn_mfma_f32_16x16x32_bf16(sf[mt][0], xf[ht][0], acc[mt * 4 + ht], 0, 0, 0);
        acc[mt * 4 + ht] = __builtin_amdgcn_mfma_f32_16x16x32_bf16(sf[mt][1], xf[ht][1], acc[mt * 4 + ht], 0, 0, 0);
      }
    __builtin_amdgcn_s_setprio(0);
#pragma unroll
    for (int mt = 0; mt < 4; ++mt)
#pragma unroll
      for (int ht = 0; ht < 4; ++ht) {                // lane: fixed h, 4 consecutive m
        floatx4 a = acc[mt * 4 + ht];
        uint2 pk; pk.x = cvtpk(a[0], a[1]); pk.y = cvtpk(a[2], a[3]);
        int h = ht * 16 + l15;
        *(uint2*)(obuf + h * 128 + ((((mt * 2 + (quad >> 1)) ^ (h & 7))) << 4) + ((quad & 1) << 3)) = pk;
      }
    BAR();                                   // out visible; R0 commits drained

    if (pre) ld_xf(xbuf, l15, quad, xf);     // X(b+1) fragments (overlaps C)

    // ---- Phase C: cooperative output; stores issue-and-continue ------------
    {
      const size_t outbase = (size_t)(bq * 4 + it) * 4096 * 256 + c0 + ch4 * 4;
#pragma unroll
      for (int rep = 0; rep < 4; ++rep) {
        int qidx = rep * 256 + grp;
        int h = qidx >> 4, mq = qidx & 15;            // m0 = mq*4
        uint loff = (uint)(h * 128 + ((((mq >> 1) ^ (h & 7))) << 4) + ((mq & 1) << 3));
        float vals[4][4];
#pragma unroll
        for (int j = 0; j < 4; ++j) {
          uint2 d = *(const uint2*)(smem + 65536 + (size_t)(ch4 * 4 + j) * 8192 + loff);
          vals[j][0] = __uint_as_float(d.x << 16);
          vals[j][1] = __uint_as_float(d.x & 0xFFFF0000u);
          vals[j][2] = __uint_as_float(d.y << 16);
          vals[j][3] = __uint_as_float(d.y & 0xFFFF0000u);
        }
        float* op = out + outbase + (size_t)(h * 64 + mq * 4) * 256;
#pragma unroll
        for (int jj = 0; jj < 4; ++jj) {
          float4 v = {vals[0][jj], vals[1][jj], vals[2][jj], vals[3][jj]};
          *(float4*)(op + (size_t)jj * 256) = v;
        }
      }
    }
    BAR();                                   // C reads done; R1/xf safe to reuse
  }
}

extern "C" void kernel_launch(void* const* d_in, const int* in_sizes, int n_in,
                              void* d_out, int out_size, void* d_ws, size_t ws_size,
                              hipStream_t stream) {
  const float* x  = (const float*)d_in[0];
  const float* Wq = (const float*)d_in[1];
  const float* Wk = (const float*)d_in[2];
  unsigned short* ws = (unsigned short*)d_ws;  // 4 MiB used
  prep_w<<<dim3(128), dim3(256), 0, stream>>>(Wq, Wk, ws);
  fused_attn<<<dim3(256), dim3(512), 0, stream>>>(x, ws, (float*)d_out);
}

// Round 6
// 361.595 us; speedup vs baseline: 1.0036x; 1.0036x over previous
//
#include <hip/hip_runtime.h>

// Fused self-attention, B=32, H=W=64, C=256.
// Block = 16 waves = 16 channels (1024 thr, full 64B-line ownership), grid = 256
// (1 block/CU), each block loops over 2 consecutive b. One WAVE per (b,c) chain.
//
// vs r5 (which regressed): fixes the two measured failures —
//  * full-line blocks: no cross-XCD half-line splitting (r5 FETCH 271->~145MB)
//  * 1024-thread block forces VGPR<=128 -> 16 waves/CU = 4/SIMD (r5 had 2/SIMD)
// and keeps the pipeline that worked:
//  * xf hoisted to regs after iter barrier -> X region dead -> X(b+1) commits
//    IN-PLACE during M1-M3 (T14 issue-early/commit-late, raw lgkm-only barriers)
//  * M1/M2/M4 ht-outer (acc 64->16 regs); Wq/Wk share one reg block (wr)
//  * M4 tail: 4 ht-quadrant passes through a 32KB bounce (LDS = 128+32 = 160KB)
//  * per-channel XOR (ch&7)<<4 on all LDS slots: staging/stream conflicts
//    4-way -> 2-way (free). Numerics identical to r3 (same formulas, order).

typedef short short8 __attribute__((ext_vector_type(8)));
typedef float floatx4 __attribute__((ext_vector_type(4)));
typedef unsigned int uint;

#define R1OFF 131072

#define BAR() do { asm volatile("s_waitcnt lgkmcnt(0)" ::: "memory"); \
    __builtin_amdgcn_s_barrier(); __builtin_amdgcn_sched_barrier(0); } while (0)

__device__ __forceinline__ uint cvtpk(float a, float b) {  // pack 2 bf16 (RNE)
  uint r;
  asm("v_cvt_pk_bf16_f32 %0, %1, %2" : "=v"(r) : "v"(a), "v"(b));
  return r;
}
__device__ __forceinline__ short8 u4s8(uint a, uint b, uint c, uint d) {
  union { uint u[4]; short8 s; } t;
  t.u[0] = a; t.u[1] = b; t.u[2] = c; t.u[3] = d;
  return t.s;
}
__device__ __forceinline__ float hsg(float x) {
  return fminf(fmaxf(0.2f * x + 0.5f, 0.f), 1.f);
}

__device__ __forceinline__ void pl32swap(uint A, uint C, uint& lo, uint& hi, int quad) {
#if __has_builtin(__builtin_amdgcn_permlane32_swap)
  auto r = __builtin_amdgcn_permlane32_swap(A, C, false, false);
  lo = (uint)r[0]; hi = (uint)r[1];
#else
  uint sA = __shfl_xor(A, 32), sC = __shfl_xor(C, 32);
  bool up = quad >= 2;
  lo = up ? sC : A;
  hi = up ? C : sA;
#endif
}
__device__ __forceinline__ void pl16swap(uint A, uint C, uint& lo, uint& hi, int quad) {
#if __has_builtin(__builtin_amdgcn_permlane16_swap)
  auto r = __builtin_amdgcn_permlane16_swap(A, C, false, false);
  lo = (uint)r[0]; hi = (uint)r[1];
#else
  uint sA = (uint)__builtin_amdgcn_ds_swizzle((int)A, 0x401F);
  uint sC = (uint)__builtin_amdgcn_ds_swizzle((int)C, 0x401F);
  bool odd = quad & 1;
  lo = odd ? sC : A;
  hi = odd ? C : sA;
#endif
}
// C-layout words (k-pair idx 8kt+2quad+r) -> A/B-frag short8 (k-pair idx 16ks+4quad+u)
__device__ __forceinline__ short8 xchg4(uint A, uint B, uint C, uint D, int quad) {
  uint Ap, Cp, Bp, Dp, t0, t1, t2, t3;
  pl32swap(A, C, Ap, Cp, quad);
  pl32swap(B, D, Bp, Dp, quad);
  pl16swap(Ap, Cp, t0, t2, quad);
  pl16swap(Bp, Dp, t1, t3, quad);
  return u4s8(t0, t1, t2, t3);
}

// staging: thread covers channels ch4*4..+3 of position-pairs grp (full 64B lines)
__device__ __forceinline__ void stage_issue(const float* xb, int grp, int bat,
                                            float4* va, float4* vb) {
#pragma unroll
  for (int i = 0; i < 4; ++i) {
    int pair = (bat * 4 + i) * 256 + grp;
    int h = pair >> 5, w0 = (pair & 31) << 1;
    const float* src = xb + (size_t)(h * 64 + w0) * 256;
    va[i] = *(const float4*)src;
    vb[i] = *(const float4*)(src + 256);
  }
}
__device__ __forceinline__ void stage_commit(unsigned char* sm, int grp, int ch4,
                                             int bat, const float4* va, const float4* vb) {
#pragma unroll
  for (int i = 0; i < 4; ++i) {
    int pair = (bat * 4 + i) * 256 + grp;
    int h = pair >> 5, w0 = (pair & 31) << 1;
    uint off = (uint)(h * 128 + (((w0 >> 3) ^ (h & 7)) << 4) + ((w0 & 7) << 1));
    uint pw[4] = {cvtpk(va[i].x, vb[i].x), cvtpk(va[i].y, vb[i].y),
                  cvtpk(va[i].z, vb[i].z), cvtpk(va[i].w, vb[i].w)};
#pragma unroll
    for (int j = 0; j < 4; ++j) {
      int ch = ch4 * 4 + j;
      *(uint*)(sm + ch * 8192 + (off ^ (uint)((ch & 7) << 4))) = pw[j];
    }
  }
}
__device__ __forceinline__ void ld_xf(const unsigned char* buf0, int l15, int quad,
                                      uint cx, short8 xf[4][2]) {
#pragma unroll
  for (int rt = 0; rt < 4; ++rt) {
    int r = rt * 16 + l15;
#pragma unroll
    for (int ks = 0; ks < 2; ++ks)
      xf[rt][ks] = *(const short8*)(buf0 + r * 128 +
                     (((uint)(((ks * 4 + quad) ^ (r & 7))) << 4) ^ cx));
  }
}

// ---- prep: Wq/Wk (C,64,64 f32) -> bf16 A-fragment layout in ws -------------
__global__ __launch_bounds__(256) void prep_w(const float* __restrict__ Wq,
                                              const float* __restrict__ Wk,
                                              unsigned short* __restrict__ ws) {
  __shared__ __align__(16) unsigned char sm[4 * 8704];
  const int tid = threadIdx.x, lane = tid & 63, wid = tid >> 6;
  const int task = blockIdx.x * 4 + wid;              // [0, 512)
  const int c = task & 255;
  const float* wp = ((task >> 8) ? Wk : Wq) + (size_t)c * 4096;
  unsigned char* buf = sm + wid * 8704;
  const int l15 = lane & 15, quad = lane >> 4;
#pragma unroll 4
  for (int j = 0; j < 16; ++j) {                      // stage [w][k], stride 136 B
    int f4 = j * 64 + lane;
    float4 v = *(const float4*)(wp + (size_t)f4 * 4);
    int w = f4 >> 4, k0 = (f4 & 15) << 2;
    uint2 pk; pk.x = cvtpk(v.x, v.y); pk.y = cvtpk(v.z, v.w);
    *(uint2*)(buf + w * 136 + k0 * 2) = pk;
  }
  unsigned short* dst = ws + (size_t)task * 4096;
#pragma unroll
  for (int kt = 0; kt < 4; ++kt)
#pragma unroll
    for (int ks = 0; ks < 2; ++ks) {                  // transposed u16 gather
      const unsigned short* p = (const unsigned short*)buf + (ks * 32 + quad * 8) * 68 + (kt * 16 + l15);
      short8 af = u4s8((uint)p[0]   | ((uint)p[68]  << 16),
                       (uint)p[136] | ((uint)p[204] << 16),
                       (uint)p[272] | ((uint)p[340] << 16),
                       (uint)p[408] | ((uint)p[476] << 16));
      *(short8*)(dst + ((kt * 2 + ks) * 64 + lane) * 8) = af;
    }
}

// ---- main ------------------------------------------------------------------
__global__ __launch_bounds__(1024) void fused_attn(
    const float* __restrict__ x, const unsigned short* __restrict__ wsp,
    float* __restrict__ out) {
  __shared__ __align__(16) unsigned char smem[163840]; // [0,128K) X; [128K,160K) out

  const int tid  = threadIdx.x;
  const int lane = tid & 63;
  const int wid  = tid >> 6;                 // 0..15 = channel within line
  const int l15  = lane & 15;
  const int quad = lane >> 4;
  const int ch4  = tid & 3;
  const int grp  = tid >> 2;                 // [0,256)

  const int cg16 = blockIdx.x & 15;          // weight-sharing blocks 16 apart
  const int bq   = blockIdx.x >> 4;          // b = bq*2 + it
  const int c0   = cg16 << 4;
  const int c    = c0 + wid;
  const uint cx  = (uint)((wid & 7) << 4);

  unsigned char* xbuf = smem + wid * 8192;

  const short8* wqf = (const short8*)wsp + (size_t)c * 512;
  const short8* wkf = wqf + 256 * 512;
  const floatx4 zero4 = {0.f, 0.f, 0.f, 0.f};

  // ---- prologue: stage X(b0) ------------------------------------------------
  {
    const float* xb = x + (size_t)(bq * 2) * 4096 * 256 + c0 + ch4 * 4;
    float4 va[4], vb[4];
    stage_issue(xb, grp, 0, va, vb);
    stage_commit(smem, grp, ch4, 0, va, vb);
    stage_issue(xb, grp, 1, va, vb);
    stage_commit(smem, grp, ch4, 1, va, vb);
  }
  BAR();
  short8 xf[4][2];
  ld_xf(xbuf, l15, quad, cx, xf);
  BAR();                                     // all xf reads done -> X region free

#pragma unroll
  for (int it = 0; it < 2; ++it) {
    const bool pre = (it == 0);
    float4 va[4], vb[4];
    const float* xbn = nullptr;
    if (pre) {
      xbn = x + (size_t)(bq * 2 + it + 1) * 4096 * 256 + c0 + ch4 * 4;
      stage_issue(xbn, grp, 0, va, vb);      // X(b+1) bat0 in flight
    }

    short8 wr[4][2];                         // Wq now, reloaded as Wk after M1
#pragma unroll
    for (int kt = 0; kt < 4; ++kt)
#pragma unroll
      for (int ks = 0; ks < 2; ++ks) wr[kt][ks] = wqf[(kt * 2 + ks) * 64 + lane];

    // ==== M1: qT = WqT x X (ht-outer, acc 16 regs) ==========================
    short8 qf[4][2];
#pragma unroll
    for (int ht = 0; ht < 4; ++ht) {
      floatx4 a4[4];
#pragma unroll
      for (int i = 0; i < 4; ++i) a4[i] = zero4;
      __builtin_amdgcn_s_setprio(1);
#pragma unroll
      for (int kt = 0; kt < 4; ++kt) {
        a4[kt] = __builtin_amdgcn_mfma_f32_16x16x32_bf16(wr[kt][0], xf[ht][0], a4[kt], 0, 0, 0);
        a4[kt] = __builtin_amdgcn_mfma_f32_16x16x32_bf16(wr[kt][1], xf[ht][1], a4[kt], 0, 0, 0);
      }
      __builtin_amdgcn_s_setprio(0);
      uint s[4][2];
#pragma unroll
      for (int kt = 0; kt < 4; ++kt) {
        s[kt][0] = cvtpk(hsg(a4[kt][0]), hsg(a4[kt][1]));
        s[kt][1] = cvtpk(hsg(a4[kt][2]), hsg(a4[kt][3]));
      }
#pragma unroll
      for (int ks = 0; ks < 2; ++ks)
        qf[ht][ks] = xchg4(s[2 * ks][0], s[2 * ks][1], s[2 * ks + 1][0], s[2 * ks + 1][1], quad);
      if (pre && ht == 0) stage_commit(smem, grp, ch4, 0, va, vb);  // in-place
      if (pre && ht == 1) stage_issue(xbn, grp, 1, va, vb);         // bat1 fly
    }

#pragma unroll
    for (int kt = 0; kt < 4; ++kt)           // reload wr as Wk (L2-resident)
#pragma unroll
      for (int ks = 0; ks < 2; ++ks) wr[kt][ks] = wkf[(kt * 2 + ks) * 64 + lane];
    if (pre) stage_commit(smem, grp, ch4, 1, va, vb);   // va/vb die before M2

    // ==== M2: KT = WkT x X (ht-outer); tanh -> kf ===========================
    short8 kf[4][2];
#pragma unroll
    for (int ht = 0; ht < 4; ++ht) {
      floatx4 a4[4];
#pragma unroll
      for (int i = 0; i < 4; ++i) a4[i] = zero4;
      __builtin_amdgcn_s_setprio(1);
#pragma unroll
      for (int kt = 0; kt < 4; ++kt) {
        a4[kt] = __builtin_amdgcn_mfma_f32_16x16x32_bf16(wr[kt][0], xf[ht][0], a4[kt], 0, 0, 0);
        a4[kt] = __builtin_amdgcn_mfma_f32_16x16x32_bf16(wr[kt][1], xf[ht][1], a4[kt], 0, 0, 0);
      }
      __builtin_amdgcn_s_setprio(0);
      uint t[4][2];
#pragma unroll
      for (int kt = 0; kt < 4; ++kt) {
        float kv[4];
#pragma unroll
        for (int i = 0; i < 4; ++i) {
          float e = __expf(2.f * a4[kt][i]);
          kv[i] = 1.f - 2.f / (e + 1.f);     // tanh
        }
        t[kt][0] = cvtpk(kv[0], kv[1]);
        t[kt][1] = cvtpk(kv[2], kv[3]);
      }
#pragma unroll
      for (int ks = 0; ks < 2; ++ks)
        kf[ht][ks] = xchg4(t[2 * ks][0], t[2 * ks][1], t[2 * ks + 1][0], t[2 * ks + 1][1], quad);
    }

    // ==== M3: S = q x K^T, softmax; two wt-half passes (acc 32 regs) ========
    short8 sf[4][2];
#pragma unroll
    for (int ks2 = 0; ks2 < 2; ++ks2) {
      floatx4 a2[8];
#pragma unroll
      for (int i = 0; i < 8; ++i) a2[i] = zero4;
      __builtin_amdgcn_s_setprio(1);
#pragma unroll
      for (int mt = 0; mt < 4; ++mt)
#pragma unroll
        for (int wtl = 0; wtl < 2; ++wtl) {
          int wt = ks2 * 2 + wtl;
          a2[wtl * 4 + mt] = __builtin_amdgcn_mfma_f32_16x16x32_bf16(qf[wt][0], kf[mt][0], a2[wtl * 4 + mt], 0, 0, 0);
          a2[wtl * 4 + mt] = __builtin_amdgcn_mfma_f32_16x16x32_bf16(qf[wt][1], kf[mt][1], a2[wtl * 4 + mt], 0, 0, 0);
        }
      __builtin_amdgcn_s_setprio(0);
      // e = exp(hs(s)); hs in [0,1] -> no max subtraction needed
#pragma unroll
      for (int i = 0; i < 8; ++i)
#pragma unroll
        for (int j = 0; j < 4; ++j) a2[i][j] = __expf(hsg(a2[i][j]));
      float inv2[2][4];
#pragma unroll
      for (int wtl = 0; wtl < 2; ++wtl)
#pragma unroll
        for (int i = 0; i < 4; ++i) {        // row sum: 3 adds + 4 shfls
          float pp = a2[wtl * 4 + 0][i] + a2[wtl * 4 + 1][i] + a2[wtl * 4 + 2][i] + a2[wtl * 4 + 3][i];
          pp += __shfl_xor(pp, 1, 16);
          pp += __shfl_xor(pp, 2, 16);
          pp += __shfl_xor(pp, 4, 16);
          pp += __shfl_xor(pp, 8, 16);
          inv2[wtl][i] = 1.f / pp;
        }
#pragma unroll
      for (int mt = 0; mt < 4; ++mt) {
        uint s0 = cvtpk(a2[mt][0] * inv2[0][0], a2[mt][1] * inv2[0][1]);
        uint s1 = cvtpk(a2[mt][2] * inv2[0][2], a2[mt][3] * inv2[0][3]);
        uint s2 = cvtpk(a2[4 + mt][0] * inv2[1][0], a2[4 + mt][1] * inv2[1][1]);
        uint s3 = cvtpk(a2[4 + mt][2] * inv2[1][2], a2[4 + mt][3] * inv2[1][3]);
        sf[mt][ks2] = xchg4(s0, s1, s2, s3, quad);
      }
    }

    // ==== M4 + output: 4 ht-quadrant passes through 32KB bounce =============
    const size_t outbase = (size_t)(bq * 2 + it) * 4096 * 256 + c0 + ch4 * 4;
#pragma unroll
    for (int ht = 0; ht < 4; ++ht) {
      floatx4 a4[4];
#pragma unroll
      for (int i = 0; i < 4; ++i) a4[i] = zero4;
      __builtin_amdgcn_s_setprio(1);
#pragma unroll
      for (int mt = 0; mt < 4; ++mt) {
        a4[mt] = __builtin_amdgcn_mfma_f32_16x16x32_bf16(sf[mt][0], xf[ht][0], a4[mt], 0, 0, 0);
        a4[mt] = __builtin_amdgcn_mfma_f32_16x16x32_bf16(sf[mt][1], xf[ht][1], a4[mt], 0, 0, 0);
      }
      __builtin_amdgcn_s_setprio(0);
#pragma unroll
      for (int mt = 0; mt < 4; ++mt) {       // lane: row l15, 4 consecutive m
        uint2 pk; pk.x = cvtpk(a4[mt][0], a4[mt][1]); pk.y = cvtpk(a4[mt][2], a4[mt][3]);
        *(uint2*)(smem + R1OFF + wid * 2048 + l15 * 128 +
                  ((uint)(((mt * 2 + (quad >> 1)) ^ (l15 & 7) ^ (wid & 7))) << 4) +
                  ((quad & 1) << 3)) = pk;
      }
      BAR();                                 // quadrant visible
      if (pre && ht == 3) ld_xf(xbuf, l15, quad, cx, xf);   // X(b+1) fragments
      {
        int r = grp >> 4, mq = grp & 15;     // 16 rows x 16 m-quads
        float vals[4][4];
#pragma unroll
        for (int j = 0; j < 4; ++j) {
          int ch = ch4 * 4 + j;
          uint2 d = *(const uint2*)(smem + R1OFF + ch * 2048 + r * 128 +
                      ((uint)(((mq >> 1) ^ (r & 7) ^ (ch & 7))) << 4) + ((mq & 1) << 3));
          vals[j][0] = __uint_as_float(d.x << 16);
          vals[j][1] = __uint_as_float(d.x & 0xFFFF0000u);
          vals[j][2] = __uint_as_float(d.y << 16);
          vals[j][3] = __uint_as_float(d.y & 0xFFFF0000u);
        }
        float* op = out + outbase + (size_t)((ht * 16 + r) * 64 + mq * 4) * 256;
#pragma unroll
        for (int jj = 0; jj < 4; ++jj) {
          float4 v = {vals[0][jj], vals[1][jj], vals[2][jj], vals[3][jj]};
          *(float4*)(op + (size_t)jj * 256) = v;
        }
      }
      BAR();                                 // quadrant reads done -> reusable
    }
  }
}

extern "C" void kernel_launch(void* const* d_in, const int* in_sizes, int n_in,
                              void* d_out, int out_size, void* d_ws, size_t ws_size,
                              hipStream_t stream) {
  const float* x  = (const float*)d_in[0];
  const float* Wq = (const float*)d_in[1];
  const float* Wk = (const float*)d_in[2];
  unsigned short* ws = (unsigned short*)d_ws;  // 4 MiB used
  prep_w<<<dim3(128), dim3(256), 0, stream>>>(Wq, Wk, ws);
  fused_attn<<<dim3(256), dim3(1024), 0, stream>>>(x, ws, (float*)d_out);
}